// Round 9
// baseline (667.064 us; speedup 1.0000x reference)
//
#include <hip/hip_runtime.h>

#define N_NODES 100000
#define N_EDGES 3200000
#define DIM 256
#define HID 128
#define NCLS 5
#define BSZ 256         // nodes per scan block
#define NBUCK 391       // ceil(N_NODES/256)
#define HPKC 16         // head-prep split-K chunk

__global__ void k_zero(int* p, int n) {
    int i = blockIdx.x * 256 + threadIdx.x;
    if (i < n) p[i] = 0;
}

// ---------------- head precompute (parallel split-K) ----------------
// Full linear collapse (network has no nonlinearities):
//   Wc  = Wm2@Wm1  [5x256];  W2c = Wc@W2  [5x256];  Wq = W2c@W1  [5x256]
//   bq  = W2c@b1 [5];  bc2 = Wc@b2 + Wm2@bm1 + bm2 [5]
template<int K>
__global__ __launch_bounds__(256) void k_hp_stage(const float* __restrict__ A,
        const float* __restrict__ B, float* __restrict__ OUT)
{
    int t = threadIdx.x;
    int k0 = blockIdx.x * HPKC;
    float acc[NCLS] = {0, 0, 0, 0, 0};
    #pragma unroll
    for (int kk = 0; kk < HPKC; ++kk) {
        int k = k0 + kk;
        float b = B[k * DIM + t];
        #pragma unroll
        for (int c = 0; c < NCLS; ++c) acc[c] += A[c * K + k] * b;
    }
    #pragma unroll
    for (int c = 0; c < NCLS; ++c) unsafeAtomicAdd(&OUT[c * DIM + t], acc[c]);
}

// biases: one wave per class (5 waves)
__global__ __launch_bounds__(320) void k_hp_bias(const float* __restrict__ Wc,
        const float* __restrict__ W2c, const float* __restrict__ Wm2,
        const float* __restrict__ b1, const float* __restrict__ b2,
        const float* __restrict__ bm1, const float* __restrict__ bm2,
        float* __restrict__ bq, float* __restrict__ bc2)
{
    int c = threadIdx.x >> 6;      // 0..4
    int lane = threadIdx.x & 63;
    float s = 0.0f;
    for (int i = lane; i < DIM; i += 64) s += W2c[c * DIM + i] * b1[i];
    #pragma unroll
    for (int off = 32; off > 0; off >>= 1) s += __shfl_xor(s, off);
    float b = 0.0f;
    for (int k = lane; k < HID; k += 64) b += Wm2[c * HID + k] * bm1[k];
    for (int o = lane; o < DIM; o += 64) b += Wc[c * DIM + o] * b2[o];
    #pragma unroll
    for (int off = 32; off > 0; off >>= 1) b += __shfl_xor(b, off);
    if (lane == 0) { bq[c] = s; bc2[c] = bm2[c] + b; }
}

// ---------------- direct CSR build ----------------
// deg[d] += 1 per edge (global int atomics onto 400 KB L2-resident array)
__global__ __launch_bounds__(1024) void k_deg(const int* __restrict__ dst,
        int* __restrict__ deg)
{
    int i = blockIdx.x * 1024 + threadIdx.x;
    int stride = gridDim.x * 1024;
    for (int e = i; e < N_EDGES; e += stride) atomicAdd(&deg[dst[e]], 1);
}

// per-block (256-node) exclusive scan of deg -> local prefix in rowptr, block totals
__global__ __launch_bounds__(256) void k_scanbuck(const int* __restrict__ deg,
        int* __restrict__ rowptr, float* __restrict__ dinv, int* __restrict__ btot)
{
    __shared__ int sdata[BSZ];
    int tid = threadIdx.x, b = blockIdx.x;
    int node = b * BSZ + tid;
    int v = (node < N_NODES) ? deg[node] : 0;
    sdata[tid] = v;
    __syncthreads();
    #pragma unroll
    for (int off = 1; off < BSZ; off <<= 1) {
        int t = (tid >= off) ? sdata[tid - off] : 0;
        __syncthreads();
        sdata[tid] += t;
        __syncthreads();
    }
    if (node < N_NODES) {
        rowptr[node] = sdata[tid] - v;   // local exclusive prefix
        dinv[node] = rsqrtf((float)(v + 1));   // +1 self-loop
    }
    if (tid == BSZ - 1) btot[b] = sdata[BSZ - 1];
}

// exclusive scan over NBUCK (=391 < 512) block totals
__global__ __launch_bounds__(512) void k_scanb(const int* __restrict__ btot,
        int* __restrict__ gbase)
{
    __shared__ int sdata[512];
    int tid = threadIdx.x;
    int v = (tid < NBUCK) ? btot[tid] : 0;
    sdata[tid] = v;
    __syncthreads();
    #pragma unroll
    for (int off = 1; off < 512; off <<= 1) {
        int t = (tid >= off) ? sdata[tid - off] : 0;
        __syncthreads();
        sdata[tid] += t;
        __syncthreads();
    }
    if (tid < NBUCK) gbase[tid] = sdata[tid] - v;   // exclusive
}

// rowptr += gbase[block]; cur = rowptr (scatter cursors)
__global__ __launch_bounds__(256) void k_fixup(const int* __restrict__ gbase,
        int* __restrict__ rowptr, int* __restrict__ cur)
{
    int b = blockIdx.x, tid = threadIdx.x;
    int node = b * BSZ + tid;
    if (node < N_NODES) {
        int rp = rowptr[node] + gbase[b];
        rowptr[node] = rp;
        cur[node] = rp;
    }
    if (b == 0 && tid == 0) rowptr[N_NODES] = N_EDGES;
}

// direct scatter: pos = cur[dst]++ (global atomic-rtn), esrc[pos] = src
// esrc is 12.8 MB -> scattered 4B writes are L2-absorbed
__global__ __launch_bounds__(1024) void k_scat(const int* __restrict__ src,
        const int* __restrict__ dst, int* __restrict__ cur, int* __restrict__ esrc)
{
    int i = blockIdx.x * 1024 + threadIdx.x;
    int stride = gridDim.x * 1024;
    for (int e = i; e < N_EDGES; e += stride) {
        int pos = atomicAdd(&cur[dst[e]], 1);
        esrc[pos] = src[e];
    }
}

// ---------------- q projection: q[s] = dinv_s * (Wq @ x[s])  (5-wide, stride 8) ----------------
__global__ __launch_bounds__(256) void k_q(const float* __restrict__ x,
        const float* __restrict__ Wq, const float* __restrict__ dinv,
        float* __restrict__ qbuf)
{
    int wid = (blockIdx.x * 256 + threadIdx.x) >> 6;   // global wave id
    int lane = threadIdx.x & 63;
    int lane4 = lane * 4;
    int nwaves = gridDim.x * 4;
    float4 w[NCLS];
    #pragma unroll
    for (int c = 0; c < NCLS; ++c) w[c] = *(const float4*)(Wq + c * DIM + lane4);
    for (int d = wid; d < N_NODES; d += nwaves) {
        float4 xv = *(const float4*)(x + (size_t)d * DIM + lane4);
        float p[NCLS];
        #pragma unroll
        for (int c = 0; c < NCLS; ++c) {
            float s = xv.x * w[c].x + xv.y * w[c].y + xv.z * w[c].z + xv.w * w[c].w;
            #pragma unroll
            for (int off = 32; off > 0; off >>= 1) s += __shfl_xor(s, off);
            p[c] = s;
        }
        if (lane == 0) {
            float dv = dinv[d];
            #pragma unroll
            for (int c = 0; c < NCLS; ++c) qbuf[(size_t)d * 8 + c] = dv * p[c];
        }
    }
}

// ---------------- 5-wide CSR aggregation (atomic-free): 4 lanes per node ----------------
// MODE 1: out[d*8+c]    = dv^2*(self + sum in[src]) + dv*bias[c]   (tbuf, stride 8)
// MODE 0: out[d*NCLS+c] = dv  *(self + sum in[src]) + bias[c]      (final, stride 5)
template<int MODE>
__global__ __launch_bounds__(256) void k_gather5(const float* __restrict__ in,
        const int* __restrict__ rowptr, const int* __restrict__ esrc,
        const float* __restrict__ dinv, const float* __restrict__ bias,
        float* __restrict__ out, int ostride)
{
    int gid = blockIdx.x * 256 + threadIdx.x;
    int d = gid >> 2, sub = gid & 3;
    if (d >= N_NODES) return;
    float acc0 = 0, acc1 = 0, acc2 = 0, acc3 = 0, acc4 = 0;
    int r0 = rowptr[d], r1 = rowptr[d + 1];
    for (int j = r0 + sub; j < r1; j += 4) {
        int s = esrc[j];
        float4 v = *(const float4*)(in + (size_t)s * 8);
        float v4 = in[(size_t)s * 8 + 4];
        acc0 += v.x; acc1 += v.y; acc2 += v.z; acc3 += v.w; acc4 += v4;
    }
    if (sub == 0) {   // self-loop
        float4 v = *(const float4*)(in + (size_t)d * 8);
        float v4 = in[(size_t)d * 8 + 4];
        acc0 += v.x; acc1 += v.y; acc2 += v.z; acc3 += v.w; acc4 += v4;
    }
    #pragma unroll
    for (int off = 1; off < 4; off <<= 1) {
        acc0 += __shfl_xor(acc0, off);
        acc1 += __shfl_xor(acc1, off);
        acc2 += __shfl_xor(acc2, off);
        acc3 += __shfl_xor(acc3, off);
        acc4 += __shfl_xor(acc4, off);
    }
    if (sub == 0) {
        float dv = dinv[d];
        float sc = (MODE == 1) ? dv * dv : dv;
        float bs = (MODE == 1) ? dv : 1.0f;
        out[(size_t)d * ostride + 0] = sc * acc0 + bs * bias[0];
        out[(size_t)d * ostride + 1] = sc * acc1 + bs * bias[1];
        out[(size_t)d * ostride + 2] = sc * acc2 + bs * bias[2];
        out[(size_t)d * ostride + 3] = sc * acc3 + bs * bias[3];
        out[(size_t)d * ostride + 4] = sc * acc4 + bs * bias[4];
    }
}

extern "C" void kernel_launch(void* const* d_in, const int* in_sizes, int n_in,
                              void* d_out, int out_size, void* d_ws, size_t ws_size,
                              hipStream_t stream)
{
    const float* x   = (const float*)d_in[0];
    const int*   ei  = (const int*)d_in[1];
    const float* W1  = (const float*)d_in[2];
    const float* b1  = (const float*)d_in[3];
    const float* W2  = (const float*)d_in[4];
    const float* b2  = (const float*)d_in[5];
    const float* Wm1 = (const float*)d_in[6];
    const float* bm1 = (const float*)d_in[7];
    const float* Wm2 = (const float*)d_in[8];
    const float* bm2 = (const float*)d_in[9];
    float* out = (float*)d_out;
    const int* src = ei;
    const int* dst = ei + N_EDGES;

    // workspace (~31 MB used; ws >= 154 MB proven)
    char* ws = (char*)d_ws;
    float* dinv     = (float*)   (ws + 0x0000000);   // 400 KB
    int* rowptr     = (int*)     (ws + 0x0080000);   // 400 KB + 4
    int* esrc       = (int*)     (ws + 0x0200000);   // 12.8 MB
    // zero region: hpw (Wq|Wc|W2c, 15 KB) + deg (400 KB), contiguous
    float* hpw      = (float*)   (ws + 0x0F00000);
    float* Wq       = hpw;                           //   5 KB
    float* Wc       = hpw + NCLS * DIM;              //   5 KB
    float* W2c      = hpw + 2 * NCLS * DIM;          //   5 KB
    int* deg        = (int*)     (hpw + 3 * NCLS * DIM);  // 400 KB
    float* bq       = (float*)   (ws + 0x0FA0000);   // 20 B
    float* bc2      = (float*)   (ws + 0x0FA1000);   // 20 B
    int* btot       = (int*)     (ws + 0x0FB0000);   // 1.6 KB
    int* gbase      = (int*)     (ws + 0x0FB2000);   // 1.6 KB
    int* cur        = (int*)     (ws + 0x0FC0000);   // 400 KB
    float* qbuf     = (float*)   (ws + 0x1100000);   // 3.2 MB (stride 8 fp32/node)
    float* tbuf     = (float*)   (ws + 0x1500000);   // 3.2 MB (stride 8 fp32/node)

    const int NZ = 3 * NCLS * DIM + N_NODES;   // hpw + deg
    k_zero<<<(NZ + 255) / 256, 256, 0, stream>>>((int*)hpw, NZ);

    // prep: fully-collapsed linear weights (Wq = (Wm2@Wm1@W2)@W1, bq, bc2)
    k_hp_stage<HID><<<HID / HPKC, 256, 0, stream>>>(Wm2, Wm1, Wc);    // Wc  = Wm2@Wm1
    k_hp_stage<DIM><<<DIM / HPKC, 256, 0, stream>>>(Wc, W2, W2c);     // W2c = Wc@W2
    k_hp_bias<<<1, 320, 0, stream>>>(Wc, W2c, Wm2, b1, b2, bm1, bm2, bq, bc2);
    k_hp_stage<DIM><<<DIM / HPKC, 256, 0, stream>>>(W2c, W1, Wq);     // Wq  = W2c@W1

    // direct CSR build: global-atomic degree + 2-level scan + direct scatter
    k_deg<<<512, 1024, 0, stream>>>(dst, deg);
    k_scanbuck<<<NBUCK, 256, 0, stream>>>(deg, rowptr, dinv, btot);
    k_scanb<<<1, 512, 0, stream>>>(btot, gbase);
    k_fixup<<<NBUCK, 256, 0, stream>>>(gbase, rowptr, cur);
    k_scat<<<512, 1024, 0, stream>>>(src, dst, cur, esrc);

    // q = dinv * (x @ Wq^T): reads x exactly once (102 MB), writes 3.2 MB
    k_q<<<2048, 256, 0, stream>>>(x, Wq, dinv, qbuf);

    const int GB = (N_NODES * 4 + 255) / 256;
    // hop 1: t[d] = dv^2*(q[d]+sum q[src]) + dv*bq   (atomic-free CSR gather)
    k_gather5<1><<<GB, 256, 0, stream>>>(qbuf, rowptr, esrc, dinv, bq, tbuf, 8);
    // hop 2: out[d] = dv*(t[d]+sum t[src]) + bc2
    k_gather5<0><<<GB, 256, 0, stream>>>(tbuf, rowptr, esrc, dinv, bc2, out, NCLS);
}

// Round 10
// 322.967 us; speedup vs baseline: 2.0654x; 2.0654x over previous
//
#include <hip/hip_runtime.h>

#define N_NODES 100000
#define N_EDGES 3200000
#define DIM 256
#define HID 128
#define NCLS 5
#define BSH 8           // bucket shift: 256 nodes per bucket
#define BSZ 256         // nodes per bucket
#define NBUCK 391       // ceil(N_NODES/256) buckets (dst>>8)
#define P1B 256         // pass-1 partition blocks
#define EPB 12500       // N_EDGES / P1B
#define HPKC 16         // head-prep split-K chunk

__global__ void k_zero(int* p, int n) {
    int i = blockIdx.x * 256 + threadIdx.x;
    if (i < n) p[i] = 0;
}

// ---------------- head precompute (parallel split-K) ----------------
// Full linear collapse (network has no nonlinearities):
//   Wc  = Wm2@Wm1  [5x256];  W2c = Wc@W2  [5x256];  Wq = W2c@W1  [5x256]
//   bq  = W2c@b1 [5];  bc2 = Wc@b2 + Wm2@bm1 + bm2 [5]
template<int K>
__global__ __launch_bounds__(256) void k_hp_stage(const float* __restrict__ A,
        const float* __restrict__ B, float* __restrict__ OUT)
{
    int t = threadIdx.x;
    int k0 = blockIdx.x * HPKC;
    float acc[NCLS] = {0, 0, 0, 0, 0};
    #pragma unroll
    for (int kk = 0; kk < HPKC; ++kk) {
        int k = k0 + kk;
        float b = B[k * DIM + t];
        #pragma unroll
        for (int c = 0; c < NCLS; ++c) acc[c] += A[c * K + k] * b;
    }
    #pragma unroll
    for (int c = 0; c < NCLS; ++c) unsafeAtomicAdd(&OUT[c * DIM + t], acc[c]);
}

// final stage: blocks 0..15 compute Wq = W2c@W1 (split-K); block 16 computes biases
__global__ __launch_bounds__(256) void k_hp_final(const float* __restrict__ W2c,
        const float* __restrict__ W1, float* __restrict__ Wq,
        const float* __restrict__ Wc, const float* __restrict__ Wm2,
        const float* __restrict__ b1, const float* __restrict__ b2,
        const float* __restrict__ bm1, const float* __restrict__ bm2,
        float* __restrict__ bq, float* __restrict__ bc2)
{
    if (blockIdx.x < DIM / HPKC) {
        int t = threadIdx.x;
        int k0 = blockIdx.x * HPKC;
        float acc[NCLS] = {0, 0, 0, 0, 0};
        #pragma unroll
        for (int kk = 0; kk < HPKC; ++kk) {
            int k = k0 + kk;
            float b = W1[k * DIM + t];
            #pragma unroll
            for (int c = 0; c < NCLS; ++c) acc[c] += W2c[c * DIM + k] * b;
        }
        #pragma unroll
        for (int c = 0; c < NCLS; ++c) unsafeAtomicAdd(&Wq[c * DIM + t], acc[c]);
    } else {
        int w = threadIdx.x >> 6, lane = threadIdx.x & 63;
        for (int c = w; c < NCLS; c += 4) {
            float s = 0.0f;
            for (int i = lane; i < DIM; i += 64) s += W2c[c * DIM + i] * b1[i];
            #pragma unroll
            for (int off = 32; off > 0; off >>= 1) s += __shfl_xor(s, off);
            float bsum = 0.0f;
            for (int k = lane; k < HID; k += 64) bsum += Wm2[c * HID + k] * bm1[k];
            for (int o = lane; o < DIM; o += 64) bsum += Wc[c * DIM + o] * b2[o];
            #pragma unroll
            for (int off = 32; off > 0; off >>= 1) bsum += __shfl_xor(bsum, off);
            if (lane == 0) { bq[c] = s; bc2[c] = bm2[c] + bsum; }
        }
    }
}

// ---------------- pass 1: coarse partition by dst>>8 (1024 thr: 16 waves/CU) ----------------
__global__ __launch_bounds__(1024) void k_p1hist(const int* __restrict__ dst,
        int* __restrict__ gcount, int* __restrict__ blockbase)
{
    __shared__ int lh[NBUCK];
    int tid = threadIdx.x;
    for (int i = tid; i < NBUCK; i += 1024) lh[i] = 0;
    __syncthreads();
    int s = blockIdx.x * EPB, e1 = s + EPB;
    for (int e = s + tid; e < e1; e += 1024) atomicAdd(&lh[dst[e] >> BSH], 1);
    __syncthreads();
    for (int i = tid; i < NBUCK; i += 1024) {
        int c = lh[i];
        blockbase[blockIdx.x * NBUCK + i] = c ? atomicAdd(&gcount[i], c) : 0;
    }
}
// exclusive scan over NBUCK (=391 < 512) bucket counts
__global__ __launch_bounds__(512) void k_scanb(const int* __restrict__ gcount,
        int* __restrict__ gbase)
{
    __shared__ int sdata[512];
    int tid = threadIdx.x;
    int v = (tid < NBUCK) ? gcount[tid] : 0;
    sdata[tid] = v;
    __syncthreads();
    #pragma unroll
    for (int off = 1; off < 512; off <<= 1) {
        int t = (tid >= off) ? sdata[tid - off] : 0;
        __syncthreads();
        sdata[tid] += t;
        __syncthreads();
    }
    if (tid < NBUCK) gbase[tid] = sdata[tid] - v;   // exclusive
    if (tid == 0) gbase[NBUCK] = N_EDGES;
}
// packed edge record: (src << 8) | (dst & 255)   [src < 2^17]
__global__ __launch_bounds__(1024) void k_p1scatter(const int* __restrict__ src,
        const int* __restrict__ dst, const int* __restrict__ gbase,
        const int* __restrict__ blockbase, unsigned* __restrict__ ebuf)
{
    __shared__ int lh[NBUCK];
    int tid = threadIdx.x;
    for (int i = tid; i < NBUCK; i += 1024) lh[i] = 0;
    __syncthreads();
    int s = blockIdx.x * EPB, e1 = s + EPB;
    for (int e = s + tid; e < e1; e += 1024) {
        int d = dst[e];
        int b = d >> BSH;
        int r = atomicAdd(&lh[b], 1);
        int pos = gbase[b] + blockbase[blockIdx.x * NBUCK + b] + r;
        ebuf[pos] = ((unsigned)src[e] << 8) | (unsigned)(d & 255);
    }
}
// ---------------- pass 2: counts -> rowptr/dinv, then per-node bucket sort ----------------
__global__ __launch_bounds__(1024) void k_p2(const unsigned* __restrict__ ebuf,
        const int* __restrict__ gbase, int* __restrict__ rowptr,
        float* __restrict__ dinv, int* __restrict__ esrc)
{
    __shared__ int c[BSZ];
    __shared__ int sdata[BSZ];
    __shared__ int cur[BSZ];
    int tid = threadIdx.x, b = blockIdx.x;
    if (tid < BSZ) c[tid] = 0;
    __syncthreads();
    int s = gbase[b], e1 = gbase[b + 1];
    for (int e = s + tid; e < e1; e += 1024) atomicAdd(&c[ebuf[e] & 255u], 1);
    __syncthreads();
    int cnt = (tid < BSZ) ? c[tid] : 0;
    if (tid < BSZ) sdata[tid] = cnt;
    __syncthreads();
    #pragma unroll
    for (int off = 1; off < BSZ; off <<= 1) {
        int t = (tid >= off && tid < BSZ) ? sdata[tid - off] : 0;
        __syncthreads();
        if (tid < BSZ) sdata[tid] += t;
        __syncthreads();
    }
    if (tid < BSZ) {
        int rp = s + sdata[tid] - cnt;   // exclusive prefix within bucket
        cur[tid] = rp;
        int node = b * BSZ + tid;
        if (node < N_NODES) {
            rowptr[node] = rp;
            dinv[node] = rsqrtf((float)(cnt + 1));   // +1 self-loop
        }
    }
    if (b == 0 && tid == 0) rowptr[N_NODES] = N_EDGES;
    __syncthreads();
    for (int e = s + tid; e < e1; e += 1024) {
        unsigned p = ebuf[e];
        int pos = atomicAdd(&cur[p & 255u], 1);
        esrc[pos] = (int)(p >> 8);
    }
}

// ---------------- q projection: q[s] = dinv_s * (Wq @ x[s])  (5-wide, stride 8) ----------------
__global__ __launch_bounds__(256) void k_q(const float* __restrict__ x,
        const float* __restrict__ Wq, const float* __restrict__ dinv,
        float* __restrict__ qbuf)
{
    int wid = (blockIdx.x * 256 + threadIdx.x) >> 6;   // global wave id
    int lane = threadIdx.x & 63;
    int lane4 = lane * 4;
    int nwaves = gridDim.x * 4;
    float4 w[NCLS];
    #pragma unroll
    for (int c = 0; c < NCLS; ++c) w[c] = *(const float4*)(Wq + c * DIM + lane4);
    for (int d = wid; d < N_NODES; d += nwaves) {
        float4 xv = *(const float4*)(x + (size_t)d * DIM + lane4);
        float p[NCLS];
        #pragma unroll
        for (int c = 0; c < NCLS; ++c) {
            float s = xv.x * w[c].x + xv.y * w[c].y + xv.z * w[c].z + xv.w * w[c].w;
            #pragma unroll
            for (int off = 32; off > 0; off >>= 1) s += __shfl_xor(s, off);
            p[c] = s;
        }
        if (lane == 0) {
            float dv = dinv[d];
            #pragma unroll
            for (int c = 0; c < NCLS; ++c) qbuf[(size_t)d * 8 + c] = dv * p[c];
        }
    }
}

// ---------------- 5-wide CSR aggregation (atomic-free): 4 lanes per node ----------------
// 2-way unrolled edge loop: two independent gather chains per lane.
// MODE 1: out[d*8+c]    = dv^2*(self + sum in[src]) + dv*bias[c]   (tbuf, stride 8)
// MODE 0: out[d*NCLS+c] = dv  *(self + sum in[src]) + bias[c]      (final, stride 5)
template<int MODE>
__global__ __launch_bounds__(256) void k_gather5(const float* __restrict__ in,
        const int* __restrict__ rowptr, const int* __restrict__ esrc,
        const float* __restrict__ dinv, const float* __restrict__ bias,
        float* __restrict__ out, int ostride)
{
    int gid = blockIdx.x * 256 + threadIdx.x;
    int d = gid >> 2, sub = gid & 3;
    if (d >= N_NODES) return;
    float acc0 = 0, acc1 = 0, acc2 = 0, acc3 = 0, acc4 = 0;
    int r0 = rowptr[d], r1 = rowptr[d + 1];
    int j = r0 + sub;
    for (; j + 4 < r1; j += 8) {
        int s0 = esrc[j];
        int s1 = esrc[j + 4];
        float4 v0 = *(const float4*)(in + (size_t)s0 * 8);
        float a0 = in[(size_t)s0 * 8 + 4];
        float4 v1 = *(const float4*)(in + (size_t)s1 * 8);
        float a1 = in[(size_t)s1 * 8 + 4];
        acc0 += v0.x + v1.x; acc1 += v0.y + v1.y; acc2 += v0.z + v1.z;
        acc3 += v0.w + v1.w; acc4 += a0 + a1;
    }
    for (; j < r1; j += 4) {
        int s = esrc[j];
        float4 v = *(const float4*)(in + (size_t)s * 8);
        float v4 = in[(size_t)s * 8 + 4];
        acc0 += v.x; acc1 += v.y; acc2 += v.z; acc3 += v.w; acc4 += v4;
    }
    if (sub == 0) {   // self-loop
        float4 v = *(const float4*)(in + (size_t)d * 8);
        float v4 = in[(size_t)d * 8 + 4];
        acc0 += v.x; acc1 += v.y; acc2 += v.z; acc3 += v.w; acc4 += v4;
    }
    #pragma unroll
    for (int off = 1; off < 4; off <<= 1) {
        acc0 += __shfl_xor(acc0, off);
        acc1 += __shfl_xor(acc1, off);
        acc2 += __shfl_xor(acc2, off);
        acc3 += __shfl_xor(acc3, off);
        acc4 += __shfl_xor(acc4, off);
    }
    if (sub == 0) {
        float dv = dinv[d];
        float sc = (MODE == 1) ? dv * dv : dv;
        float bs = (MODE == 1) ? dv : 1.0f;
        out[(size_t)d * ostride + 0] = sc * acc0 + bs * bias[0];
        out[(size_t)d * ostride + 1] = sc * acc1 + bs * bias[1];
        out[(size_t)d * ostride + 2] = sc * acc2 + bs * bias[2];
        out[(size_t)d * ostride + 3] = sc * acc3 + bs * bias[3];
        out[(size_t)d * ostride + 4] = sc * acc4 + bs * bias[4];
    }
}

extern "C" void kernel_launch(void* const* d_in, const int* in_sizes, int n_in,
                              void* d_out, int out_size, void* d_ws, size_t ws_size,
                              hipStream_t stream)
{
    const float* x   = (const float*)d_in[0];
    const int*   ei  = (const int*)d_in[1];
    const float* W1  = (const float*)d_in[2];
    const float* b1  = (const float*)d_in[3];
    const float* W2  = (const float*)d_in[4];
    const float* b2  = (const float*)d_in[5];
    const float* Wm1 = (const float*)d_in[6];
    const float* bm1 = (const float*)d_in[7];
    const float* Wm2 = (const float*)d_in[8];
    const float* bm2 = (const float*)d_in[9];
    float* out = (float*)d_out;
    const int* src = ei;
    const int* dst = ei + N_EDGES;

    // workspace (~40 MB used; ws >= 154 MB proven)
    char* ws = (char*)d_ws;
    float* dinv     = (float*)   (ws + 0x0000000);   // 400 KB
    int* rowptr     = (int*)     (ws + 0x0080000);   // 400 KB + 4
    int* esrc       = (int*)     (ws + 0x0200000);   // 12.8 MB
    // hpw (Wq|Wc|W2c, 15 KB) and gcount (1.6 KB) contiguous: one k_zero covers both
    float* hpw      = (float*)   (ws + 0x0F00000);
    float* Wq       = hpw;                           //   5 KB
    float* Wc       = hpw + NCLS * DIM;              //   5 KB
    float* W2c      = hpw + 2 * NCLS * DIM;          //   5 KB
    int* gcount     = (int*)     (hpw + 3 * NCLS * DIM);  // 1.6 KB
    float* bq       = (float*)   (ws + 0x0F10000);   // 20 B
    float* bc2      = (float*)   (ws + 0x0F11000);   // 20 B
    float* qbuf     = (float*)   (ws + 0x1000000);   // 3.2 MB (stride 8 fp32/node)
    float* tbuf     = (float*)   (ws + 0x1400000);   // 3.2 MB (stride 8 fp32/node)
    unsigned* ebuf  = (unsigned*)(ws + 0x1800000);   // 12.8 MB (packed src<<8|dst8)
    int* blockbase  = (int*)     (ws + 0x2600000);   // 400 KB (P1B x NBUCK)
    int* gbase      = (int*)     (ws + 0x2700000);   // 1.6 KB

    const int NZ = 3 * NCLS * DIM + NBUCK;   // hpw + gcount
    k_zero<<<(NZ + 255) / 256, 256, 0, stream>>>((int*)hpw, NZ);

    // prep: fully-collapsed linear weights (Wq = (Wm2@Wm1@W2)@W1, bq, bc2)
    k_hp_stage<HID><<<HID / HPKC, 256, 0, stream>>>(Wm2, Wm1, Wc);    // Wc  = Wm2@Wm1
    k_hp_stage<DIM><<<DIM / HPKC, 256, 0, stream>>>(Wc, W2, W2c);     // W2c = Wc@W2
    k_hp_final<<<DIM / HPKC + 1, 256, 0, stream>>>(W2c, W1, Wq,       // Wq + biases
            Wc, Wm2, b1, b2, bm1, bm2, bq, bc2);

    // 2-level radix CSR build (256-node buckets: 128 B scatter chunks)
    k_p1hist<<<P1B, 1024, 0, stream>>>(dst, gcount, blockbase);
    k_scanb<<<1, 512, 0, stream>>>(gcount, gbase);
    k_p1scatter<<<P1B, 1024, 0, stream>>>(src, dst, gbase, blockbase, ebuf);
    k_p2<<<NBUCK, 1024, 0, stream>>>(ebuf, gbase, rowptr, dinv, esrc);

    // q = dinv * (x @ Wq^T): reads x exactly once (102 MB), writes 3.2 MB
    k_q<<<2048, 256, 0, stream>>>(x, Wq, dinv, qbuf);

    const int GB = (N_NODES * 4 + 255) / 256;
    // hop 1: t[d] = dv^2*(q[d]+sum q[src]) + dv*bq   (atomic-free CSR gather)
    k_gather5<1><<<GB, 256, 0, stream>>>(qbuf, rowptr, esrc, dinv, bq, tbuf, 8);
    // hop 2: out[d] = dv*(t[d]+sum t[src]) + bc2
    k_gather5<0><<<GB, 256, 0, stream>>>(tbuf, rowptr, esrc, dinv, bc2, out, NCLS);
}